// Round 4
// baseline (290.519 us; speedup 1.0000x reference)
//
#include <hip/hip_runtime.h>
#include <cmath>

#define GAMMA 0.9865f
#define L2G   -0.01960905f   // log2(0.9865)
#define BATCH 8
#define SEQ   4000
#define CSUP  25
#define GSUP  32
#define RPG   125            // rows per superchunk = 5*CSUP

typedef _Float16 half8 __attribute__((ext_vector_type(8)));
typedef _Float16 half4 __attribute__((ext_vector_type(4)));
typedef float    floatx4 __attribute__((ext_vector_type(4)));

__device__ __forceinline__ float gpow(float e) { return exp2f(e * L2G); }  // GAMMA^e

// ---------------- Kernel 0: transpose+convert W -> Wt[mat][n][k] fp16
__global__ __launch_bounds__(256) void wt_convert(
    const float* __restrict__ Wq, const float* __restrict__ Wk, const float* __restrict__ Wv,
    _Float16* __restrict__ Wt) {
    int t = blockIdx.x * 256 + threadIdx.x;           // 3*65536
    int mat = t >> 16, rem = t & 65535;
    int n = rem >> 8, k = rem & 255;
    const float* W = (mat == 0) ? Wq : (mat == 1) ? Wk : Wv;
    Wt[(size_t)mat * 65536 + n * 256 + k] = (_Float16)W[k * 256 + n];
}

// ---------------- Kernel 1: QKV projection, fp16 MFMA.  dst = x @ W  (M=32000,N=256,K=256)
__global__ __launch_bounds__(256, 2) void qkv_gemm_f16(
    const float* __restrict__ xq, const float* __restrict__ xk, const float* __restrict__ xv,
    const _Float16* __restrict__ WtAll,
    _Float16* __restrict__ Qb, _Float16* __restrict__ Kb, _Float16* __restrict__ Vb) {
    int op = blockIdx.y;
    const float* x = (op == 0) ? xq : (op == 1) ? xk : xv;
    const _Float16* Wt = WtAll + (size_t)op * 65536;
    _Float16* dst = (op == 0) ? Qb : (op == 1) ? Kb : Vb;

    __shared__ _Float16 Xs[128][40];
    __shared__ _Float16 WsT[256][40];

    int t = threadIdx.x;
    int lane = t & 63, wave = t >> 6;
    int ln = lane & 15, q8 = (lane >> 4) << 3, q4 = (lane >> 4) << 2;
    int row0 = blockIdx.x * 128;

    floatx4 acc[8][4] = {};

    for (int dt = 0; dt < 8; ++dt) {
        int k0 = dt * 32;
#pragma unroll
        for (int i = 0; i < 4; ++i) {
            int idx = t + i * 256;
            int m = idx >> 3, kk = (idx & 7) << 2;
            floatx4 v = *(const floatx4*)&x[(size_t)(row0 + m) * 256 + k0 + kk];
            half4 h; h[0] = (_Float16)v[0]; h[1] = (_Float16)v[1];
            h[2] = (_Float16)v[2]; h[3] = (_Float16)v[3];
            *(half4*)&Xs[m][kk] = h;
        }
#pragma unroll
        for (int i = 0; i < 4; ++i) {
            int idx = t + i * 256;
            int n = idx >> 2, kk = (idx & 3) << 3;
            *(half8*)&WsT[n][kk] = *(const half8*)&Wt[n * 256 + k0 + kk];
        }
        __syncthreads();
        half8 af[8];
#pragma unroll
        for (int mi = 0; mi < 8; ++mi) af[mi] = *(const half8*)&Xs[mi * 16 + ln][q8];
#pragma unroll
        for (int ni = 0; ni < 4; ++ni) {
            half8 bf = *(const half8*)&WsT[(wave * 4 + ni) * 16 + ln][q8];
#pragma unroll
            for (int mi = 0; mi < 8; ++mi)
                acc[mi][ni] = __builtin_amdgcn_mfma_f32_16x16x32_f16(af[mi], bf, acc[mi][ni], 0, 0, 0);
        }
        __syncthreads();
    }
#pragma unroll
    for (int mi = 0; mi < 8; ++mi)
#pragma unroll
        for (int ni = 0; ni < 4; ++ni)
#pragma unroll
            for (int r = 0; r < 4; ++r) {
                int row = row0 + mi * 16 + q4 + r;
                int col = (wave * 4 + ni) * 16 + ln;
                dst[(size_t)row * 256 + col] = (_Float16)acc[mi][ni][r];
            }
}

// ---------------- Kernel 2: chunk states via MFMA.
// Wh[g][b][e][d] (fp16) = sum_r V[r][e]*alpha'(r) * K[r][d], alpha' = g^(149-6*mloc).
// Odd-halfword row strides (137/265) so scalar transposed stores + fragment gathers are conflict-free.
__global__ __launch_bounds__(256, 2) void chunk_states_mfma(
    const _Float16* __restrict__ Kb, const _Float16* __restrict__ Vb,
    _Float16* __restrict__ Wh) {
    int eh = blockIdx.x, g = blockIdx.y, b = blockIdx.z;
    int t = threadIdx.x, lane = t & 63, wave = t >> 6;
    int ln = lane & 15, q8 = (lane >> 4) << 3, q4 = (lane >> 4) << 2;
    __shared__ _Float16 Vs[32 * 137];
    __shared__ _Float16 Ks[32 * 265];
    size_t base_row = (size_t)b * SEQ + g * RPG;
    floatx4 acc[8][4] = {};
    for (int kt = 0; kt < 4; ++kt) {
        int r0 = kt * 32;
#pragma unroll
        for (int i = 0; i < 2; ++i) {          // Vs[r][e] with alpha (scalar stores, conflict-free)
            int idx = t + i * 256;
            int r = idx >> 4, e8 = (idx & 15) << 3;
            half8 v = {};
            if (r0 + r < RPG) {
                v = *(const half8*)&Vb[(base_row + r0 + r) * 256 + eh * 128 + e8];
                int mloc = (r0 + r) / 5;
                float a = gpow((float)(149 - 6 * mloc));
#pragma unroll
                for (int z = 0; z < 8; ++z) v[z] = (_Float16)((float)v[z] * a);
            }
#pragma unroll
            for (int z = 0; z < 8; ++z) Vs[r * 137 + e8 + z] = v[z];
        }
#pragma unroll
        for (int i = 0; i < 4; ++i) {          // Ks[r][d]
            int idx = t + i * 256;
            int r = idx >> 5, d8 = (idx & 31) << 3;
            half8 v = {};
            if (r0 + r < RPG) v = *(const half8*)&Kb[(base_row + r0 + r) * 256 + d8];
#pragma unroll
            for (int z = 0; z < 8; ++z) Ks[r * 265 + d8 + z] = v[z];
        }
        __syncthreads();
        half8 Af[8], Bf[4];
#pragma unroll
        for (int mi = 0; mi < 8; ++mi)
#pragma unroll
            for (int j = 0; j < 8; ++j) Af[mi][j] = Vs[(q8 + j) * 137 + mi * 16 + ln];
#pragma unroll
        for (int ni = 0; ni < 4; ++ni)
#pragma unroll
            for (int j = 0; j < 8; ++j) Bf[ni][j] = Ks[(q8 + j) * 265 + wave * 64 + ni * 16 + ln];
#pragma unroll
        for (int mi = 0; mi < 8; ++mi)
#pragma unroll
            for (int ni = 0; ni < 4; ++ni)
                acc[mi][ni] = __builtin_amdgcn_mfma_f32_16x16x32_f16(Af[mi], Bf[ni], acc[mi][ni], 0, 0, 0);
        __syncthreads();
    }
    size_t ob = ((size_t)(g * 8 + b)) << 16;
#pragma unroll
    for (int mi = 0; mi < 8; ++mi)
#pragma unroll
        for (int ni = 0; ni < 4; ++ni)
#pragma unroll
            for (int r = 0; r < 4; ++r) {
                int e = eh * 128 + mi * 16 + q4 + r;
                int d = wave * 64 + ni * 16 + ln;
                Wh[ob + (size_t)e * 256 + d] = (_Float16)acc[mi][ni][r];
            }
}

// ---------------- Kernel 3: exclusive scan over g (fp16 in/out, fp32 accum). 512 blocks.
__global__ __launch_bounds__(256) void state_scan(
    const _Float16* __restrict__ Wh, _Float16* __restrict__ SprevT) {
    int t = blockIdx.x * 256 + threadIdx.x;   // 131072 threads
    int b = t >> 14;
    int idx = (t & 16383) << 2;               // 4 consecutive halves
    const float gF = gpow(150.0f);
    float s[4] = {};
    for (int g = 0; g < GSUP; ++g) {
        size_t o = (((size_t)(g * 8 + b)) << 16) + idx;
        half4 w = *(const half4*)&Wh[o];
        half4 sv;
#pragma unroll
        for (int z = 0; z < 4; ++z) { sv[z] = (_Float16)s[z]; s[z] = (float)w[z] + gF * s[z]; }
        *(half4*)&SprevT[o] = sv;
    }
}

// ---------------- Kernel 4: intra score matrices, pre-scaled by gamma^(q-p).
__global__ __launch_bounds__(256) void intra_sc(
    const _Float16* __restrict__ Qb, const _Float16* __restrict__ Kb, float* __restrict__ scw) {
    int b = blockIdx.y;
    int j = blockIdx.x * 4 + (threadIdx.x >> 6);
    int lane = threadIdx.x & 63;
    size_t base = ((size_t)b * SEQ + j * 5) * 256 + lane * 4;
    half4 qv[5], kv[5];
#pragma unroll
    for (int p = 0; p < 5; ++p) {
        qv[p] = *(const half4*)&Qb[base + p * 256];
        kv[p] = *(const half4*)&Kb[base + p * 256];
    }
#pragma unroll
    for (int p = 0; p < 5; ++p)
#pragma unroll
        for (int q = 0; q <= p; ++q) {
            float s = 0.f;
#pragma unroll
            for (int z = 0; z < 4; ++z) s += (float)qv[p][z] * (float)kv[q][z];
#pragma unroll
            for (int off = 32; off; off >>= 1) s += __shfl_xor(s, off, 64);
            if (lane == 0) scw[((size_t)b * 800 + j) * 25 + p * 5 + q] = s * gpow((float)(q - p));
        }
}

// ---------------- Kernel 5: cross + fused intra epilogue. Direct-global MFMA fragments:
// no LDS staging / no barriers in the K-loop. LDS: P round-trip + V^T only (stride 130, odd).
// grid (4 e-quarters, 32 g, 8 b); out = rowscale*(Q'@S') + (mask o (Q'@K^T))@V + intra
__global__ __launch_bounds__(256, 3) void cross_f16(
    const _Float16* __restrict__ Qb, const _Float16* __restrict__ Kb,
    const _Float16* __restrict__ Vb, const _Float16* __restrict__ SprevT,
    const float* __restrict__ scw, float* __restrict__ out) {
    int eq = blockIdx.x, g = blockIdx.y, b = blockIdx.z;
    int e0 = eq * 64;
    int t = threadIdx.x;
    int lane = t & 63, wave = t >> 6;
    int ln = lane & 15, q8 = (lane >> 4) << 3, q4 = (lane >> 4) << 2;
    int m4 = (wave >> 1) * 4;      // row-half
    int c4 = (wave & 1) * 4;       // cp-half for P
    int e2 = (wave & 1) * 2;       // e-pair for acc

    __shared__ float rtab[25];          // gamma^(6rc+7)
    __shared__ float gtabm[25];         // gamma^(6(i+1))
    __shared__ _Float16 PsB[128 * 130]; // P, row stride 130 halves (odd -> conflict-free scalar ops)
    __shared__ _Float16 VsB[64 * 130];  // V^T[e][cp]

    if (t < 25) { rtab[t] = gpow((float)(6 * t + 7)); gtabm[t] = gpow((float)(6 * (t + 1))); }

    size_t kvbase = (size_t)b * SEQ + g * RPG;
    size_t sb = ((size_t)(g * 8 + b)) << 16;
    size_t qrow0 = (size_t)b * SEQ;

    // stage V^T (independent of K-loop; visible after S1)
#pragma unroll
    for (int i = 0; i < 4; ++i) {
        int idx = t + i * 256;
        int cp = idx >> 3, e8 = (idx & 7) << 3;
        half8 v = {};
        if (cp < 125) v = *(const half8*)&Vb[(kvbase + cp) * 256 + e0 + e8];
#pragma unroll
        for (int z = 0; z < 8; ++z) VsB[(e8 + z) * 130 + cp] = v[z];
    }

    floatx4 pacc[4][4] = {};
    floatx4 acc[4][2] = {};

    // ---- K-loop: all fragments direct from global, zero barriers
    for (int dt = 0; dt < 8; ++dt) {
        int d0 = dt * 32;
        half8 af[4];
#pragma unroll
        for (int mi = 0; mi < 4; ++mi) {
            int rp = (m4 + mi) * 16 + ln;
            int qr = g * RPG + 5 + rp;
            half8 v = {};
            if (rp < 125 && qr < SEQ) v = *(const half8*)&Qb[(qrow0 + qr) * 256 + d0 + q8];
            af[mi] = v;
        }
#pragma unroll
        for (int ci = 0; ci < 4; ++ci) {
            int cp = (c4 + ci) * 16 + ln;
            half8 bf = {};
            if (cp < 125) bf = *(const half8*)&Kb[(kvbase + cp) * 256 + d0 + q8];
#pragma unroll
            for (int mi = 0; mi < 4; ++mi)
                pacc[mi][ci] = __builtin_amdgcn_mfma_f32_16x16x32_f16(af[mi], bf, pacc[mi][ci], 0, 0, 0);
        }
#pragma unroll
        for (int ei = 0; ei < 2; ++ei) {
            half8 bf = *(const half8*)&SprevT[sb + (size_t)(e0 + (e2 + ei) * 16 + ln) * 256 + d0 + q8];
#pragma unroll
            for (int mi = 0; mi < 4; ++mi)
                acc[mi][ei] = __builtin_amdgcn_mfma_f32_16x16x32_f16(af[mi], bf, acc[mi][ei], 0, 0, 0);
        }
    }

    __syncthreads();   // S1: tables + VsB visible

    // rowscale on the S-part
#pragma unroll
    for (int mi = 0; mi < 4; ++mi)
#pragma unroll
        for (int r = 0; r < 4; ++r) {
            int rp = (m4 + mi) * 16 + q4 + r;
            int rc = rp / 5;
            float rs = 0.f;
            if (rp < 125 && !(g == GSUP - 1 && rc == CSUP - 1)) rs = rtab[rc];
            acc[mi][0][r] *= rs;
            acc[mi][1][r] *= rs;
        }

    // masked P -> LDS (fp16)
#pragma unroll
    for (int mi = 0; mi < 4; ++mi)
#pragma unroll
        for (int ci = 0; ci < 4; ++ci)
#pragma unroll
            for (int r = 0; r < 4; ++r) {
                int rp = (m4 + mi) * 16 + q4 + r;
                int cp = (c4 + ci) * 16 + ln;
                int rc = rp / 5, cc = cp / 5;
                float w = 0.f;
                if (rp < 125 && cp < 125 && cc <= rc && !(g == GSUP - 1 && rc == CSUP - 1))
                    w = gtabm[rc - cc];
                PsB[rp * 130 + cp] = (_Float16)(pacc[mi][ci][r] * w);
            }
    __syncthreads();   // S2

    // PV: acc += P @ V_loc (scalar gathers, odd stride -> conflict-free)
#pragma unroll
    for (int ct = 0; ct < 4; ++ct) {
        int cp0 = ct * 32;
        half8 paf[4];
#pragma unroll
        for (int mi = 0; mi < 4; ++mi)
#pragma unroll
            for (int j = 0; j < 8; ++j)
                paf[mi][j] = PsB[((m4 + mi) * 16 + ln) * 130 + cp0 + q8 + j];
#pragma unroll
        for (int ei = 0; ei < 2; ++ei) {
            half8 bv;
#pragma unroll
            for (int j = 0; j < 8; ++j)
                bv[j] = VsB[((e2 + ei) * 16 + ln) * 130 + cp0 + q8 + j];
#pragma unroll
            for (int mi = 0; mi < 4; ++mi)
                acc[mi][ei] = __builtin_amdgcn_mfma_f32_16x16x32_f16(paf[mi], bv, acc[mi][ei], 0, 0, 0);
        }
    }

    // epilogue: add intra term from scw + VsB, single fp32 store
#pragma unroll
    for (int mi = 0; mi < 4; ++mi)
#pragma unroll
        for (int r = 0; r < 4; ++r) {
            int rp = (m4 + mi) * 16 + q4 + r;
            if (rp < 125) {
                int rc = rp / 5, pp = rp - rc * 5;
                const float* srow = scw + ((size_t)b * 800 + g * 25 + rc) * 25 + pp * 5;
                float a0 = acc[mi][0][r], a1 = acc[mi][1][r];
                for (int q = 0; q <= pp; ++q) {
                    float s = srow[q];
                    a0 += s * (float)VsB[(e2 * 16 + ln) * 130 + rc * 5 + q];
                    a1 += s * (float)VsB[((e2 + 1) * 16 + ln) * 130 + rc * 5 + q];
                }
                size_t orow = ((size_t)b * SEQ + g * RPG + rp) * 256;
                out[orow + e0 + e2 * 16 + ln] = a0;
                out[orow + e0 + (e2 + 1) * 16 + ln] = a1;
            }
        }
}

extern "C" void kernel_launch(void* const* d_in, const int* in_sizes, int n_in,
                              void* d_out, int out_size, void* d_ws, size_t ws_size,
                              hipStream_t stream) {
    const float* xq = (const float*)d_in[0];
    const float* xk = (const float*)d_in[1];
    const float* xv = (const float*)d_in[2];
    const float* Wq = (const float*)d_in[3];
    const float* Wk = (const float*)d_in[4];
    const float* Wv = (const float*)d_in[5];
    float* out = (float*)d_out;

    const size_t NELEM = (size_t)SEQ * BATCH * 256;   // 8,192,000
    _Float16* Qb = (_Float16*)d_ws;
    _Float16* Kb = Qb + NELEM;
    _Float16* Vb = Kb + NELEM;
    _Float16* Wt = Vb + NELEM;                              // 196,608 halves
    _Float16* Wh = Wt + 196608;                             // [g][b][e][d] fp16, 33.5 MB
    _Float16* SprevT = Wh + (size_t)GSUP * BATCH * 65536;   // fp16, 33.5 MB
    float* scw = (float*)(SprevT + (size_t)GSUP * BATCH * 65536);  // 640 KB

    wt_convert<<<dim3(768), 256, 0, stream>>>(Wq, Wk, Wv, Wt);
    qkv_gemm_f16<<<dim3(250, 3), 256, 0, stream>>>(xq, xk, xv, Wt, Qb, Kb, Vb);
    chunk_states_mfma<<<dim3(2, 32, 8), 256, 0, stream>>>(Kb, Vb, Wh);
    state_scan<<<dim3(512), 256, 0, stream>>>(Wh, SprevT);
    intra_sc<<<dim3(200, 8), 256, 0, stream>>>(Qb, Kb, scw);
    cross_f16<<<dim3(4, 32, 8), 256, 0, stream>>>(Qb, Kb, Vb, SprevT, scw, out);
}

// Round 5
// 277.505 us; speedup vs baseline: 1.0469x; 1.0469x over previous
//
#include <hip/hip_runtime.h>
#include <cmath>

#define GAMMA 0.9865f
#define L2G   -0.01960905f   // log2(0.9865)
#define BATCH 8
#define SEQ   4000
#define CSUP  25
#define GSUP  32
#define RPG   125            // rows per superchunk = 5*CSUP

typedef _Float16 half8 __attribute__((ext_vector_type(8)));
typedef _Float16 half4 __attribute__((ext_vector_type(4)));
typedef float    floatx4 __attribute__((ext_vector_type(4)));

__device__ __forceinline__ float gpow(float e) { return exp2f(e * L2G); }  // GAMMA^e

// ---------------- Kernel 0: transpose+convert W -> Wt[mat][n][k] fp16
__global__ __launch_bounds__(256) void wt_convert(
    const float* __restrict__ Wq, const float* __restrict__ Wk, const float* __restrict__ Wv,
    _Float16* __restrict__ Wt) {
    int t = blockIdx.x * 256 + threadIdx.x;           // 3*65536
    int mat = t >> 16, rem = t & 65535;
    int n = rem >> 8, k = rem & 255;
    const float* W = (mat == 0) ? Wq : (mat == 1) ? Wk : Wv;
    Wt[(size_t)mat * 65536 + n * 256 + k] = (_Float16)W[k * 256 + n];
}

// ---------------- Kernel 1: QKV projection, fp16 MFMA.  dst = x @ W  (M=32000,N=256,K=256)
__global__ __launch_bounds__(256, 2) void qkv_gemm_f16(
    const float* __restrict__ xq, const float* __restrict__ xk, const float* __restrict__ xv,
    const _Float16* __restrict__ WtAll,
    _Float16* __restrict__ Qb, _Float16* __restrict__ Kb, _Float16* __restrict__ Vb) {
    int op = blockIdx.y;
    const float* x = (op == 0) ? xq : (op == 1) ? xk : xv;
    const _Float16* Wt = WtAll + (size_t)op * 65536;
    _Float16* dst = (op == 0) ? Qb : (op == 1) ? Kb : Vb;

    __shared__ _Float16 Xs[128][40];
    __shared__ _Float16 WsT[256][40];

    int t = threadIdx.x;
    int lane = t & 63, wave = t >> 6;
    int ln = lane & 15, q8 = (lane >> 4) << 3, q4 = (lane >> 4) << 2;
    int row0 = blockIdx.x * 128;

    floatx4 acc[8][4] = {};

    for (int dt = 0; dt < 8; ++dt) {
        int k0 = dt * 32;
#pragma unroll
        for (int i = 0; i < 4; ++i) {
            int idx = t + i * 256;
            int m = idx >> 3, kk = (idx & 7) << 2;
            floatx4 v = *(const floatx4*)&x[(size_t)(row0 + m) * 256 + k0 + kk];
            half4 h; h[0] = (_Float16)v[0]; h[1] = (_Float16)v[1];
            h[2] = (_Float16)v[2]; h[3] = (_Float16)v[3];
            *(half4*)&Xs[m][kk] = h;
        }
#pragma unroll
        for (int i = 0; i < 4; ++i) {
            int idx = t + i * 256;
            int n = idx >> 2, kk = (idx & 3) << 3;
            *(half8*)&WsT[n][kk] = *(const half8*)&Wt[n * 256 + k0 + kk];
        }
        __syncthreads();
        half8 af[8];
#pragma unroll
        for (int mi = 0; mi < 8; ++mi) af[mi] = *(const half8*)&Xs[mi * 16 + ln][q8];
#pragma unroll
        for (int ni = 0; ni < 4; ++ni) {
            half8 bf = *(const half8*)&WsT[(wave * 4 + ni) * 16 + ln][q8];
#pragma unroll
            for (int mi = 0; mi < 8; ++mi)
                acc[mi][ni] = __builtin_amdgcn_mfma_f32_16x16x32_f16(af[mi], bf, acc[mi][ni], 0, 0, 0);
        }
        __syncthreads();
    }
#pragma unroll
    for (int mi = 0; mi < 8; ++mi)
#pragma unroll
        for (int ni = 0; ni < 4; ++ni)
#pragma unroll
            for (int r = 0; r < 4; ++r) {
                int row = row0 + mi * 16 + q4 + r;
                int col = (wave * 4 + ni) * 16 + ln;
                dst[(size_t)row * 256 + col] = (_Float16)acc[mi][ni][r];
            }
}

// ---------------- Kernel 2: chunk states via MFMA (odd-stride LDS, conflict-free).
// Wh[g][b][e][d] (fp16) = sum_r V[r][e]*alpha'(r) * K[r][d], alpha' = g^(149-6*mloc).
__global__ __launch_bounds__(256, 2) void chunk_states_mfma(
    const _Float16* __restrict__ Kb, const _Float16* __restrict__ Vb,
    _Float16* __restrict__ Wh) {
    int eh = blockIdx.x, g = blockIdx.y, b = blockIdx.z;
    int t = threadIdx.x, lane = t & 63, wave = t >> 6;
    int ln = lane & 15, q8 = (lane >> 4) << 3, q4 = (lane >> 4) << 2;
    __shared__ _Float16 Vs[32 * 137];
    __shared__ _Float16 Ks[32 * 265];
    size_t base_row = (size_t)b * SEQ + g * RPG;
    floatx4 acc[8][4] = {};
    for (int kt = 0; kt < 4; ++kt) {
        int r0 = kt * 32;
#pragma unroll
        for (int i = 0; i < 2; ++i) {
            int idx = t + i * 256;
            int r = idx >> 4, e8 = (idx & 15) << 3;
            half8 v = {};
            if (r0 + r < RPG) {
                v = *(const half8*)&Vb[(base_row + r0 + r) * 256 + eh * 128 + e8];
                int mloc = (r0 + r) / 5;
                float a = gpow((float)(149 - 6 * mloc));
#pragma unroll
                for (int z = 0; z < 8; ++z) v[z] = (_Float16)((float)v[z] * a);
            }
#pragma unroll
            for (int z = 0; z < 8; ++z) Vs[r * 137 + e8 + z] = v[z];
        }
#pragma unroll
        for (int i = 0; i < 4; ++i) {
            int idx = t + i * 256;
            int r = idx >> 5, d8 = (idx & 31) << 3;
            half8 v = {};
            if (r0 + r < RPG) v = *(const half8*)&Kb[(base_row + r0 + r) * 256 + d8];
#pragma unroll
            for (int z = 0; z < 8; ++z) Ks[r * 265 + d8 + z] = v[z];
        }
        __syncthreads();
        half8 Af[8], Bf[4];
#pragma unroll
        for (int mi = 0; mi < 8; ++mi)
#pragma unroll
            for (int j = 0; j < 8; ++j) Af[mi][j] = Vs[(q8 + j) * 137 + mi * 16 + ln];
#pragma unroll
        for (int ni = 0; ni < 4; ++ni)
#pragma unroll
            for (int j = 0; j < 8; ++j) Bf[ni][j] = Ks[(q8 + j) * 265 + wave * 64 + ni * 16 + ln];
#pragma unroll
        for (int mi = 0; mi < 8; ++mi)
#pragma unroll
            for (int ni = 0; ni < 4; ++ni)
                acc[mi][ni] = __builtin_amdgcn_mfma_f32_16x16x32_f16(Af[mi], Bf[ni], acc[mi][ni], 0, 0, 0);
        __syncthreads();
    }
    size_t ob = ((size_t)(g * 8 + b)) << 16;
#pragma unroll
    for (int mi = 0; mi < 8; ++mi)
#pragma unroll
        for (int ni = 0; ni < 4; ++ni)
#pragma unroll
            for (int r = 0; r < 4; ++r) {
                int e = eh * 128 + mi * 16 + q4 + r;
                int d = wave * 64 + ni * 16 + ln;
                Wh[ob + (size_t)e * 256 + d] = (_Float16)acc[mi][ni][r];
            }
}

// ---------------- Kernel 3: exclusive scan over g; output in MFMA-FRAGMENT ORDER:
// Sx[g][b][ T*512 + (e&15)*32 + (d&31) ], T = (d>>5)*16 + (e>>4)
// so cross can read B-fragments directly from global, fully coalesced.
__global__ __launch_bounds__(256) void state_scan(
    const _Float16* __restrict__ Wh, _Float16* __restrict__ Sx) {
    int t = blockIdx.x * 256 + threadIdx.x;   // 131072 threads
    int b = t >> 14;
    int r = t & 16383;
    int e = r >> 6;
    int dc = (r & 63) << 2;
    int T = (dc >> 5) * 16 + (e >> 4);
    int off = T * 512 + (e & 15) * 32 + (dc & 31);
    const float gF = gpow(150.0f);
    float s[4] = {};
    for (int g = 0; g < GSUP; ++g) {
        size_t ibase = ((size_t)(g * 8 + b)) << 16;
        half4 w = *(const half4*)&Wh[ibase + e * 256 + dc];
        half4 sv;
#pragma unroll
        for (int z = 0; z < 4; ++z) { sv[z] = (_Float16)s[z]; s[z] = (float)w[z] + gF * s[z]; }
        *(half4*)&Sx[ibase + off] = sv;
    }
}

// ---------------- Kernel 4: intra score matrices, pre-scaled by gamma^(q-p).
__global__ __launch_bounds__(256) void intra_sc(
    const _Float16* __restrict__ Qb, const _Float16* __restrict__ Kb, float* __restrict__ scw) {
    int b = blockIdx.y;
    int j = blockIdx.x * 4 + (threadIdx.x >> 6);
    int lane = threadIdx.x & 63;
    size_t base = ((size_t)b * SEQ + j * 5) * 256 + lane * 4;
    half4 qv[5], kv[5];
#pragma unroll
    for (int p = 0; p < 5; ++p) {
        qv[p] = *(const half4*)&Qb[base + p * 256];
        kv[p] = *(const half4*)&Kb[base + p * 256];
    }
#pragma unroll
    for (int p = 0; p < 5; ++p)
#pragma unroll
        for (int q = 0; q <= p; ++q) {
            float s = 0.f;
#pragma unroll
            for (int z = 0; z < 4; ++z) s += (float)qv[p][z] * (float)kv[q][z];
#pragma unroll
            for (int off = 32; off; off >>= 1) s += __shfl_xor(s, off, 64);
            if (lane == 0) scw[((size_t)b * 800 + j) * 25 + p * 5 + q] = s * gpow((float)(q - p));
        }
}

// ---------------- Kernel 5: cross + fused intra. grid (2 row-halves, 32 g, 8 b), 256 thr.
// Block: 64 out-rows x 256 e. Q/K double-buffered LDS; S' fragments direct from global
// (fragment-order layout); P->LDS; V^T in 2 e-half passes reusing staging region.
__global__ __launch_bounds__(256, 3) void cross_f16(
    const _Float16* __restrict__ Qb, const _Float16* __restrict__ Kb,
    const _Float16* __restrict__ Vb, const _Float16* __restrict__ Sx,
    const float* __restrict__ scw, float* __restrict__ out) {
    int rh = blockIdx.x, g = blockIdx.y, b = blockIdx.z;
    int t = threadIdx.x;
    int lane = t & 63, eq = t >> 6;                   // wave id = e-quarter
    int ln = lane & 15, qd = lane >> 4;
    int q8 = qd << 3, q4 = qd << 2;

    // LDS: [0,34816) staging union (dbuf Q/K 2x15360; later V^T 128x136)
    //      [34816,52224) PsB 64x136 fp16 ; [52224,..) rtab/gtabm
    __shared__ __align__(16) char smem[52432];
    _Float16* stage = (_Float16*)smem;
    _Float16* PsB = (_Float16*)(smem + 34816);
    float* rtab = (float*)(smem + 52224);
    float* gtabm = rtab + 25;

    if (t < 25) { rtab[t] = gpow((float)(6 * t + 7)); gtabm[t] = gpow((float)(6 * (t + 1))); }

    size_t kvbase = (size_t)b * SEQ + g * RPG;
    size_t sxb = ((size_t)(g * 8 + b)) << 16;
    size_t qtop = (size_t)b * SEQ;

    // staging thread mapping
    int sm = t >> 2;                 // 0..63
    int skk = (t & 3) << 3;          // 0/8/16/24
    int rpgQ = rh * 64 + sm;
    int qr = g * RPG + 5 + rpgQ;
    bool qok = (rpgQ < RPG) && (qr < SEQ);
    int cpb = sm + 64;

    floatx4 pacc[4][2] = {};
    floatx4 acc[4][4] = {};

    // stage dt=0 into buf0
    {
        half8 pq = {}, pk0, pk1 = {};
        if (qok) pq = *(const half8*)&Qb[(qtop + qr) * 256 + skk];
        pk0 = *(const half8*)&Kb[(kvbase + sm) * 256 + skk];
        if (cpb < RPG) pk1 = *(const half8*)&Kb[(kvbase + cpb) * 256 + skk];
        *(half8*)&stage[sm * 40 + skk] = pq;
        *(half8*)&stage[2560 + sm * 40 + skk] = pk0;
        *(half8*)&stage[2560 + cpb * 40 + skk] = pk1;
    }
    __syncthreads();

#pragma unroll
    for (int dt = 0; dt < 8; ++dt) {
        const _Float16* Qc = stage + (dt & 1) * 7680;
        const _Float16* Kc = Qc + 2560;
        // prefetch next chunk into regs
        half8 pq = {}, pk0 = {}, pk1 = {};
        if (dt < 7) {
            int d0n = (dt + 1) * 32;
            if (qok) pq = *(const half8*)&Qb[(qtop + qr) * 256 + d0n + skk];
            pk0 = *(const half8*)&Kb[(kvbase + sm) * 256 + d0n + skk];
            if (cpb < RPG) pk1 = *(const half8*)&Kb[(kvbase + cpb) * 256 + d0n + skk];
        }
        // S fragments for this dt: direct global, coalesced (fragment-order layout)
        half8 sf[4];
#pragma unroll
        for (int ei = 0; ei < 4; ++ei) {
            int Et = (ei >> 1) * 8 + eq * 2 + (ei & 1);
            sf[ei] = *(const half8*)&Sx[sxb + (size_t)(dt * 16 + Et) * 512 + ln * 32 + q8];
        }
        half8 af[4];
#pragma unroll
        for (int mi = 0; mi < 4; ++mi) af[mi] = *(const half8*)&Qc[(mi * 16 + ln) * 40 + q8];
#pragma unroll
        for (int ci = 0; ci < 2; ++ci) {
            half8 bk = *(const half8*)&Kc[(eq * 32 + ci * 16 + ln) * 40 + q8];
#pragma unroll
            for (int mi = 0; mi < 4; ++mi)
                pacc[mi][ci] = __builtin_amdgcn_mfma_f32_16x16x32_f16(af[mi], bk, pacc[mi][ci], 0, 0, 0);
        }
#pragma unroll
        for (int ei = 0; ei < 4; ++ei)
#pragma unroll
            for (int mi = 0; mi < 4; ++mi)
                acc[mi][ei] = __builtin_amdgcn_mfma_f32_16x16x32_f16(af[mi], sf[ei], acc[mi][ei], 0, 0, 0);
        if (dt < 7) {
            _Float16* Qn = stage + ((dt + 1) & 1) * 7680;
            *(half8*)&Qn[sm * 40 + skk] = pq;
            *(half8*)&Qn[2560 + sm * 40 + skk] = pk0;
            *(half8*)&Qn[2560 + cpb * 40 + skk] = pk1;
        }
        __syncthreads();
    }

    // rowscale on the S-part
#pragma unroll
    for (int mi = 0; mi < 4; ++mi)
#pragma unroll
        for (int r = 0; r < 4; ++r) {
            int rpg = rh * 64 + mi * 16 + q4 + r;
            float rs = 0.f;
            if (rpg < RPG) {
                int rc = rpg / 5;
                if (!(g == GSUP - 1 && rc == CSUP - 1)) rs = rtab[rc];
            }
#pragma unroll
            for (int ei = 0; ei < 4; ++ei) acc[mi][ei][r] *= rs;
        }

    // masked P -> LDS (stage region is dead: safe after final K-loop barrier)
#pragma unroll
    for (int mi = 0; mi < 4; ++mi)
#pragma unroll
        for (int ci = 0; ci < 2; ++ci)
#pragma unroll
            for (int r = 0; r < 4; ++r) {
                int rpl = mi * 16 + q4 + r;
                int rpg = rh * 64 + rpl;
                int cp = eq * 32 + ci * 16 + ln;
                float w = 0.f;
                if (rpg < RPG && cp < RPG) {
                    int rc = rpg / 5, cc = cp / 5;
                    if (cc <= rc && !(g == GSUP - 1 && rc == CSUP - 1)) w = gtabm[rc - cc];
                }
                PsB[rpl * 136 + cp] = (_Float16)(pacc[mi][ci][r] * w);
            }

    _Float16* VsT = (_Float16*)smem;   // [128 e][136 cp]

    // two e-half passes: stage V^T, PV, intra epilogue, store
#pragma unroll
    for (int h = 0; h < 2; ++h) {
        if (h == 1) __syncthreads();   // wait pass-0 reads before restage
        // stage V^T half: conflict-free scatter (lanes -> consecutive cp)
#pragma unroll
        for (int i = 0; i < 8; ++i) {
            int idx = t + i * 256;
            int cp = idx & 127;
            int eb = idx >> 7;         // 0..15
            half8 v = {};
            if (cp < RPG) v = *(const half8*)&Vb[(kvbase + cp) * 256 + h * 128 + eb * 8];
#pragma unroll
            for (int z = 0; z < 8; ++z) VsT[(eb * 8 + z) * 136 + cp] = v[z];
        }
        __syncthreads();
        // PV for this half
#pragma unroll
        for (int ct = 0; ct < 4; ++ct) {
            half8 ap[4];
#pragma unroll
            for (int mi = 0; mi < 4; ++mi)
                ap[mi] = *(const half8*)&PsB[(mi * 16 + ln) * 136 + ct * 32 + q8];
#pragma unroll
            for (int j = 0; j < 2; ++j) {
                half8 bv = *(const half8*)&VsT[(eq * 32 + j * 16 + ln) * 136 + ct * 32 + q8];
#pragma unroll
                for (int mi = 0; mi < 4; ++mi)
                    acc[mi][h * 2 + j] = __builtin_amdgcn_mfma_f32_16x16x32_f16(ap[mi], bv, acc[mi][h * 2 + j], 0, 0, 0);
            }
        }
        // epilogue: intra + store
#pragma unroll
        for (int mi = 0; mi < 4; ++mi)
#pragma unroll
            for (int r = 0; r < 4; ++r) {
                int rpg = rh * 64 + mi * 16 + q4 + r;
                if (rpg < RPG) {
                    int rc = rpg / 5, pp = rpg - rc * 5;
                    const float* srow = scw + ((size_t)b * 800 + g * 25 + rc) * 25 + pp * 5;
#pragma unroll
                    for (int j = 0; j < 2; ++j) {
                        int el = eq * 32 + j * 16 + ln;
                        float a = acc[mi][h * 2 + j][r];
                        for (int q = 0; q <= pp; ++q)
                            a += srow[q] * (float)VsT[el * 136 + rc * 5 + q];
                        out[((size_t)b * SEQ + g * RPG + rpg) * 256 + h * 128 + el] = a;
                    }
                }
            }
    }
}

extern "C" void kernel_launch(void* const* d_in, const int* in_sizes, int n_in,
                              void* d_out, int out_size, void* d_ws, size_t ws_size,
                              hipStream_t stream) {
    const float* xq = (const float*)d_in[0];
    const float* xk = (const float*)d_in[1];
    const float* xv = (const float*)d_in[2];
    const float* Wq = (const float*)d_in[3];
    const float* Wk = (const float*)d_in[4];
    const float* Wv = (const float*)d_in[5];
    float* out = (float*)d_out;

    const size_t NELEM = (size_t)SEQ * BATCH * 256;   // 8,192,000
    _Float16* Qb = (_Float16*)d_ws;
    _Float16* Kb = Qb + NELEM;
    _Float16* Vb = Kb + NELEM;
    _Float16* Wt = Vb + NELEM;                              // 196,608 halves
    _Float16* Wh = Wt + 196608;                             // [g][b][e][d] fp16, 33.5 MB
    _Float16* Sx = Wh + (size_t)GSUP * BATCH * 65536;       // fragment-order S', 33.5 MB
    float* scw = (float*)(Sx + (size_t)GSUP * BATCH * 65536);  // 640 KB

    wt_convert<<<dim3(768), 256, 0, stream>>>(Wq, Wk, Wv, Wt);
    qkv_gemm_f16<<<dim3(250, 3), 256, 0, stream>>>(xq, xk, xv, Wt, Qb, Kb, Vb);
    chunk_states_mfma<<<dim3(2, 32, 8), 256, 0, stream>>>(Kb, Vb, Wh);
    state_scan<<<dim3(512), 256, 0, stream>>>(Wh, Sx);
    intra_sc<<<dim3(200, 8), 256, 0, stream>>>(Qb, Kb, scw);
    cross_f16<<<dim3(2, 32, 8), 256, 0, stream>>>(Qb, Kb, Vb, Sx, scw, out);
}